// Round 1
// 395.716 us; speedup vs baseline: 1.0424x; 1.0424x over previous
//
#include <hip/hip_runtime.h>
#include <hip/hip_bf16.h>
#include <stdint.h>

#define QL 1024
#define KL 1024
#define HM 64
#define DD 128
#define SM_SCALE 0.08838834764831845f

typedef __bf16 bf16x8 __attribute__((ext_vector_type(8)));
typedef __bf16 bf16x4 __attribute__((ext_vector_type(4)));
typedef float floatx4 __attribute__((ext_vector_type(4)));

typedef __attribute__((address_space(1))) const uint32_t gl_u32;
typedef __attribute__((address_space(3))) uint32_t lds_u32;

// =====================================================================
// prep: fp32 [row][g][d] -> bf16, chunk-major per 128-row tile:
//   dst elem offset = (((g*8 + rt)*16 + c)*128 + r)*8 + e
//   (c = 16B chunk 0..15, r = row-in-tile 0..127, e = 0..7)
// Q tensor at ws elem 0, K tensor at ws elem 2^23 (16 MB each).
// Mapping is source-coalesced (c fastest); dest 64B lines are fully
// covered within each wave (4 consecutive r per c) -> full-line writes.
// =====================================================================
__global__ __launch_bounds__(256)
void prep_kernel(const float* __restrict__ Q, const float* __restrict__ K,
                 __bf16* __restrict__ ws)
{
    const int tid = blockIdx.x * 256 + threadIdx.x;      // 0 .. 2^21-1
    const float* src = (tid >> 20) ? K : Q;
    __bf16* dst = ws + ((size_t)(tid >> 20) << 23);
    const int rem = tid & 0xFFFFF;
    const int c  = rem & 15;
    const int r  = (rem >> 4) & 127;
    const int rt = (rem >> 11) & 7;
    const int g  = rem >> 14;
    const int row = rt * 128 + r;

    const float* s = src + (((size_t)row * HM + g) << 7) + (c << 3);
    float4 a = *(const float4*)s;
    float4 b = *(const float4*)(s + 4);
    bf16x8 v = { (__bf16)a.x, (__bf16)a.y, (__bf16)a.z, (__bf16)a.w,
                 (__bf16)b.x, (__bf16)b.y, (__bf16)b.z, (__bf16)b.w };
    const size_t dchunk = ((size_t)(g * 8 + rt) * 16 + c) * 128 + r;
    *(bf16x8*)(dst + dchunk * 8) = v;
}

// =====================================================================
// main QK kernel: one 128x128 tile per block, 4 waves of 64x64.
//  - linear global_load_lds staging (layout pre-swizzled by prep)
//  - swapped-operand MFMA -> lane holds 4 consecutive k -> float4 epilogue
//  - sink column fused into kt==7 blocks
//  - XCD-chunked block mapping: bid&7 -> XCD gets 8 contiguous g slices
// =====================================================================
__global__ __launch_bounds__(256, 2)
void qk2_kernel(const __bf16* __restrict__ ws, const float* __restrict__ mask,
                const float* __restrict__ sinks, float* __restrict__ out)
{
    const int bid  = blockIdx.x;          // 0..4095
    const int lin  = bid >> 3;            // 0..511
    const int g    = ((bid & 7) << 3) + (lin >> 6);
    const int tile = lin & 63;
    const int qt = tile >> 3;
    const int kt = tile & 7;

    __shared__ __bf16 As[16384];          // 32 KB, chunk-major
    __shared__ __bf16 Bs[16384];

    const int t    = threadIdx.x;
    const int wave = t >> 6;
    const int lane = t & 63;

    const __bf16* Aso = ws + ((size_t)(g * 8 + qt) << 14);
    const __bf16* Bso = ws + ((size_t)1 << 23) + ((size_t)(g * 8 + kt) << 14);

    // ---- async stage: 2 x 32 KB, pure linear DMA, no VALU ----
    {
        const char* ga = (const char*)Aso + wave * 1024 + lane * 16;
        const char* gb = (const char*)Bso + wave * 1024 + lane * 16;
        char* la = (char*)As + wave * 1024;
        char* lb = (char*)Bs + wave * 1024;
#pragma unroll
        for (int j = 0; j < 8; ++j) {
            __builtin_amdgcn_global_load_lds((gl_u32*)(ga + j * 4096),
                                             (lds_u32*)(la + j * 4096), 16, 0, 0);
            __builtin_amdgcn_global_load_lds((gl_u32*)(gb + j * 4096),
                                             (lds_u32*)(lb + j * 4096), 16, 0, 0);
        }
    }
    __syncthreads();   // drains vmcnt before LDS reads

    // ---- compute: swapped operands mfma(K,Q) ----
    const int wm   = (wave & 1) << 6;     // q offset of wave
    const int wn   = (wave >> 1) << 6;    // k offset of wave
    const int lr   = lane & 15;
    const int quad = lane >> 4;

    floatx4 acc[4][4] = {};
#pragma unroll
    for (int ks = 0; ks < 4; ++ks) {
        const int cb = ((ks << 2) + quad) << 7;   // chunk*128 rows
        bf16x8 af[4], bfr[4];
#pragma unroll
        for (int mi = 0; mi < 4; ++mi)
            af[mi] = *(const bf16x8*)&As[(size_t)(cb + wm + mi * 16 + lr) << 3];
#pragma unroll
        for (int ni = 0; ni < 4; ++ni)
            bfr[ni] = *(const bf16x8*)&Bs[(size_t)(cb + wn + ni * 16 + lr) << 3];
#pragma unroll
        for (int mi = 0; mi < 4; ++mi)
#pragma unroll
            for (int ni = 0; ni < 4; ++ni)
                acc[mi][ni] = __builtin_amdgcn_mfma_f32_16x16x32_bf16(
                    bfr[ni], af[mi], acc[mi][ni], 0, 0, 0);
    }

    // ---- epilogue: C/D col=lane&15 -> q, row=quad*4+r -> k (swapped) ----
    // lane holds 4 consecutive k: float4 mask load + float4 store
    const size_t obase = (size_t)g * QL * 1025;
#pragma unroll
    for (int mi = 0; mi < 4; ++mi) {
        const int q = (qt << 7) + wm + mi * 16 + lr;
        const float* mrow = mask + ((size_t)q << 10);
        float* orow = out + obase + (size_t)q * 1025;
#pragma unroll
        for (int ni = 0; ni < 4; ++ni) {
            const int k0 = (kt << 7) + wn + ni * 16 + (quad << 2);
            floatx4 mv = *(const floatx4*)(mrow + k0);       // 16B aligned
            floatx4 v  = acc[mi][ni] * SM_SCALE + mv;
            __builtin_memcpy((void*)(orow + k0), &v, 16);    // 4B-aligned dwordx4
        }
    }

    // ---- fused sink column ----
    if (kt == 7 && t < 128) {
        const int q = (qt << 7) + t;
        out[obase + (size_t)q * 1025 + 1024] = sinks[(g << 10) + q];
    }
}

// =====================================================================
// fallback path (ws too small): previous verified kernels
// =====================================================================
#define BM 128
#define BN 128
#define LDPAD 136

__global__ __launch_bounds__(256, 2)
void qk_kernel(const float* __restrict__ Qg, const float* __restrict__ Kg,
               const float* __restrict__ mask, float* __restrict__ out)
{
    const int g    = blockIdx.y;
    const int tile = blockIdx.x;
    const int qt = (tile >> 3) * BM;
    const int kt = (tile & 7) * BN;

    __shared__ __bf16 Asf[BM][LDPAD];
    __shared__ __bf16 Bsf[BN][LDPAD];

    const int t = threadIdx.x;
    const float* Ag = Qg + (size_t)qt * (HM * DD) + (size_t)g * DD;
    const float* Bg = Kg + (size_t)kt * (HM * DD) + (size_t)g * DD;
#pragma unroll
    for (int j = 0; j < 16; ++j) {
        int c = t + 256 * j;
        int row = c >> 5;
        int c4  = c & 31;
        float4 a = *(const float4*)(Ag + (size_t)row * (HM * DD) + c4 * 4);
        float4 b = *(const float4*)(Bg + (size_t)row * (HM * DD) + c4 * 4);
        bf16x4 av = { (__bf16)a.x, (__bf16)a.y, (__bf16)a.z, (__bf16)a.w };
        bf16x4 bv = { (__bf16)b.x, (__bf16)b.y, (__bf16)b.z, (__bf16)b.w };
        *(bf16x4*)&Asf[row][c4 * 4] = av;
        *(bf16x4*)&Bsf[row][c4 * 4] = bv;
    }
    __syncthreads();

    const int wave = t >> 6;
    const int lane = t & 63;
    const int wm = (wave & 1) * 64;
    const int wn = (wave >> 1) * 64;
    const int lr = lane & 15;
    const int quad = lane >> 4;

    floatx4 acc[4][4] = {};
#pragma unroll
    for (int ks = 0; ks < 4; ++ks) {
        const int d0 = ks * 32 + quad * 8;
        bf16x8 af[4], bf[4];
#pragma unroll
        for (int mi = 0; mi < 4; ++mi)
            af[mi] = *(const bf16x8*)&Asf[wm + mi * 16 + lr][d0];
#pragma unroll
        for (int ni = 0; ni < 4; ++ni)
            bf[ni] = *(const bf16x8*)&Bsf[wn + ni * 16 + lr][d0];
#pragma unroll
        for (int mi = 0; mi < 4; ++mi)
#pragma unroll
            for (int ni = 0; ni < 4; ++ni)
                acc[mi][ni] = __builtin_amdgcn_mfma_f32_16x16x32_bf16(
                    af[mi], bf[ni], acc[mi][ni], 0, 0, 0);
    }

    const size_t obase = (size_t)g * QL * 1025;
#pragma unroll
    for (int mi = 0; mi < 4; ++mi) {
#pragma unroll
        for (int r = 0; r < 4; ++r) {
            int q = qt + wm + mi * 16 + quad * 4 + r;
            const float* mrow = mask + (size_t)q * KL;
            float* orow = out + obase + (size_t)q * 1025;
#pragma unroll
            for (int ni = 0; ni < 4; ++ni) {
                int k = kt + wn + ni * 16 + lr;
                orow[k] = acc[mi][ni][r] * SM_SCALE + mrow[k];
            }
        }
    }
}

__global__ void sink_kernel(const float* __restrict__ sinks, float* __restrict__ out)
{
    int idx = blockIdx.x * 256 + threadIdx.x;
    out[(size_t)idx * 1025 + 1024] = sinks[idx];
}

extern "C" void kernel_launch(void* const* d_in, const int* in_sizes, int n_in,
                              void* d_out, int out_size, void* d_ws, size_t ws_size,
                              hipStream_t stream)
{
    const float* Q     = (const float*)d_in[0];
    const float* K     = (const float*)d_in[1];
    const float* mask  = (const float*)d_in[2];
    const float* sinks = (const float*)d_in[3];
    float* out = (float*)d_out;

    if (d_ws && ws_size >= (size_t)(2u * 8388608u * sizeof(__bf16))) {
        __bf16* ws = (__bf16*)d_ws;
        prep_kernel<<<8192, 256, 0, stream>>>(Q, K, ws);
        qk2_kernel<<<4096, 256, 0, stream>>>(ws, mask, sinks, out);
    } else {
        sink_kernel<<<(HM * QL) / 256, 256, 0, stream>>>(sinks, out);
        qk_kernel<<<dim3(64, 64), 256, 0, stream>>>(Q, K, mask, out);
    }
}